// Round 2
// baseline (423.939 us; speedup 1.0000x reference)
//
#include <hip/hip_runtime.h>

#define N_NODES 50000
#define NFEAT 64

// ---------------- CSR build ----------------

__global__ __launch_bounds__(256) void k_hist(const int* __restrict__ dst, int E,
                                              int* __restrict__ counts) {
    int e = blockIdx.x * 256 + threadIdx.x;
    if (e < E) atomicAdd(&counts[dst[e]], 1);
}

// Single-block exclusive scan over 50000 counts -> offs[0..N], also seeds cursor.
__global__ __launch_bounds__(1024) void k_scan(const int* __restrict__ counts,
                                               int* __restrict__ offs,
                                               int* __restrict__ cursor) {
    __shared__ int ssum[1024];
    const int C = (N_NODES + 1023) / 1024;  // 49 nodes per thread
    int t = threadIdx.x;
    int base = t * C;
    int s = 0;
    for (int i = 0; i < C; ++i) {
        int idx = base + i;
        if (idx < N_NODES) s += counts[idx];
    }
    ssum[t] = s;
    __syncthreads();
    // Hillis-Steele inclusive scan over 1024 partials
    for (int off = 1; off < 1024; off <<= 1) {
        int v = (t >= off) ? ssum[t - off] : 0;
        __syncthreads();
        if (t >= off) ssum[t] += v;
        __syncthreads();
    }
    int run = ssum[t] - s;  // exclusive prefix for this thread's chunk
    for (int i = 0; i < C; ++i) {
        int idx = base + i;
        if (idx < N_NODES) {
            offs[idx] = run;
            cursor[idx] = run;
            run += counts[idx];
        }
    }
    if (t == 1023) offs[N_NODES] = ssum[1023];
}

__global__ __launch_bounds__(256) void k_scatter(const int* __restrict__ src,
                                                 const int* __restrict__ dst,
                                                 const float* __restrict__ w, int E,
                                                 int* __restrict__ cursor,
                                                 int2* __restrict__ pairs) {
    int e = blockIdx.x * 256 + threadIdx.x;
    if (e < E) {
        int d = dst[e];
        int pos = atomicAdd(&cursor[d], 1);
        pairs[pos] = make_int2(src[e], __float_as_int(w[e]));
    }
}

// ---------------- SpMM: one wave per dst node, lane = feature ----------------

__global__ __launch_bounds__(256) void k_spmm(const int* __restrict__ offs,
                                              const int2* __restrict__ pairs,
                                              const float* __restrict__ Hin,
                                              float* __restrict__ Hout) {
    int wid = (blockIdx.x * 256 + threadIdx.x) >> 6;  // node id
    int lane = threadIdx.x & 63;                      // feature id
    if (wid >= N_NODES) return;
    int beg = offs[wid], end = offs[wid + 1];
    float acc0 = 0.f, acc1 = 0.f, acc2 = 0.f, acc3 = 0.f;
    int e = beg;
    for (; e + 4 <= end; e += 4) {  // 4 gathers in flight
        int2 p0 = pairs[e];
        int2 p1 = pairs[e + 1];
        int2 p2 = pairs[e + 2];
        int2 p3 = pairs[e + 3];
        acc0 = fmaf(__int_as_float(p0.y), Hin[(size_t)p0.x * NFEAT + lane], acc0);
        acc1 = fmaf(__int_as_float(p1.y), Hin[(size_t)p1.x * NFEAT + lane], acc1);
        acc2 = fmaf(__int_as_float(p2.y), Hin[(size_t)p2.x * NFEAT + lane], acc2);
        acc3 = fmaf(__int_as_float(p3.y), Hin[(size_t)p3.x * NFEAT + lane], acc3);
    }
    for (; e < end; ++e) {
        int2 p = pairs[e];
        acc0 = fmaf(__int_as_float(p.y), Hin[(size_t)p.x * NFEAT + lane], acc0);
    }
    Hout[(size_t)wid * NFEAT + lane] = (acc0 + acc1) + (acc2 + acc3);
}

// ---------------- Dense epilogue: out = H @ W + b (fp32, vector ALU) ----------------

#define FMA4(A, S, V)                                                          \
    do {                                                                       \
        A.x = fmaf(S, V.x, A.x);                                               \
        A.y = fmaf(S, V.y, A.y);                                               \
        A.z = fmaf(S, V.z, A.z);                                               \
        A.w = fmaf(S, V.w, A.w);                                               \
    } while (0)

__global__ __launch_bounds__(256) void k_gemm(const float* __restrict__ Hin,
                                              const float* __restrict__ W,
                                              const float* __restrict__ b,
                                              float* __restrict__ out) {
    __shared__ float4 WL[64 * 16];  // W[i][j4], 16 KiB
    __shared__ float4 BL[16];
    int t = threadIdx.x;
    const float4* W4 = (const float4*)W;
    for (int k = t; k < 1024; k += 256) WL[k] = W4[k];
    if (t < 16) BL[t] = ((const float4*)b)[t];
    __syncthreads();
    int n = blockIdx.x * 256 + t;  // one node per thread
    if (n >= N_NODES) return;
    const float4* Hrow = (const float4*)(Hin + (size_t)n * NFEAT);
    float4 acc[16];
#pragma unroll
    for (int j = 0; j < 16; ++j) acc[j] = BL[j];
    for (int i4 = 0; i4 < 16; ++i4) {  // dynamic outer loop, static acc indexing inside
        float4 h = Hrow[i4];
        const float4* w0 = &WL[(i4 * 4 + 0) * 16];
        const float4* w1 = &WL[(i4 * 4 + 1) * 16];
        const float4* w2 = &WL[(i4 * 4 + 2) * 16];
        const float4* w3 = &WL[(i4 * 4 + 3) * 16];
#pragma unroll
        for (int j = 0; j < 16; ++j) {
            FMA4(acc[j], h.x, w0[j]);
            FMA4(acc[j], h.y, w1[j]);
            FMA4(acc[j], h.z, w2[j]);
            FMA4(acc[j], h.w, w3[j]);
        }
    }
    float4* o = (float4*)(out + (size_t)n * NFEAT);
#pragma unroll
    for (int j = 0; j < 16; ++j) o[j] = acc[j];
}

// ---------------- launch ----------------

extern "C" void kernel_launch(void* const* d_in, const int* in_sizes, int n_in,
                              void* d_out, int out_size, void* d_ws, size_t ws_size,
                              hipStream_t stream) {
    const int* edge_index = (const int*)d_in[0];
    const float* ew = (const float*)d_in[1];
    const float* H = (const float*)d_in[2];
    const float* W = (const float*)d_in[3];
    const float* b = (const float*)d_in[4];
    float* out = (float*)d_out;

    int E = in_sizes[1];              // 800000
    const int* src = edge_index;      // [2,E] row-major: row 0 = src
    const int* dst = edge_index + E;  // row 1 = dst

    // workspace carve-out (~32.6 MB total)
    char* ws = (char*)d_ws;
    size_t off = 0;
    auto alloc = [&](size_t bytes) -> void* {
        void* p = ws + off;
        off += (bytes + 255) & ~(size_t)255;
        return p;
    };
    int* counts = (int*)alloc((size_t)N_NODES * 4);
    int* offs = (int*)alloc(((size_t)N_NODES + 1) * 4);
    int* cursor = (int*)alloc((size_t)N_NODES * 4);
    int2* pairs = (int2*)alloc((size_t)E * 8);
    float* bufA = (float*)alloc((size_t)N_NODES * NFEAT * 4);
    float* bufB = (float*)alloc((size_t)N_NODES * NFEAT * 4);

    hipMemsetAsync(counts, 0, (size_t)N_NODES * 4, stream);

    int eb = (E + 255) / 256;
    k_hist<<<eb, 256, 0, stream>>>(dst, E, counts);
    k_scan<<<1, 1024, 0, stream>>>(counts, offs, cursor);
    k_scatter<<<eb, 256, 0, stream>>>(src, dst, ew, E, cursor, pairs);

    int nb = (N_NODES * 64 + 255) / 256;  // 4 nodes (waves) per block
    k_spmm<<<nb, 256, 0, stream>>>(offs, pairs, H, bufA);
    k_spmm<<<nb, 256, 0, stream>>>(offs, pairs, bufA, bufB);
    k_spmm<<<nb, 256, 0, stream>>>(offs, pairs, bufB, bufA);

    k_gemm<<<(N_NODES + 255) / 256, 256, 0, stream>>>(bufA, W, b, out);
}

// Round 3
// 310.359 us; speedup vs baseline: 1.3660x; 1.3660x over previous
//
#include <hip/hip_runtime.h>

#define N_NODES 50000
#define NFEAT 64
#define SCAN_NB ((N_NODES + 255) / 256)  // 196 blocks

// ---------------- CSR build ----------------

__global__ __launch_bounds__(256) void k_hist(const int* __restrict__ dst, int E,
                                              int* __restrict__ counts) {
    int e = blockIdx.x * 256 + threadIdx.x;
    if (e < E) atomicAdd(&counts[dst[e]], 1);
}

// Phase A: per-block inclusive scan of 256 counts; write per-element
// exclusive-within-block prefix and the block total.
__global__ __launch_bounds__(256) void k_scan_a(const int* __restrict__ counts,
                                                int* __restrict__ local_ex,
                                                int* __restrict__ blockSums) {
    __shared__ int s[256];
    int t = threadIdx.x;
    int i = blockIdx.x * 256 + t;
    int v = (i < N_NODES) ? counts[i] : 0;
    s[t] = v;
    __syncthreads();
    for (int off = 1; off < 256; off <<= 1) {
        int u = (t >= off) ? s[t - off] : 0;
        __syncthreads();
        if (t >= off) s[t] += u;
        __syncthreads();
    }
    if (i < N_NODES) local_ex[i] = s[t] - v;
    if (t == 255) blockSums[blockIdx.x] = s[255];
}

// Phase B: one block scans the 196 block sums -> exclusive blockPrefix.
__global__ __launch_bounds__(256) void k_scan_b(const int* __restrict__ blockSums,
                                                int* __restrict__ blockPrefix) {
    __shared__ int s[256];
    int t = threadIdx.x;
    int v = (t < SCAN_NB) ? blockSums[t] : 0;
    s[t] = v;
    __syncthreads();
    for (int off = 1; off < 256; off <<= 1) {
        int u = (t >= off) ? s[t - off] : 0;
        __syncthreads();
        if (t >= off) s[t] += u;
        __syncthreads();
    }
    if (t < SCAN_NB) blockPrefix[t] = s[t] - v;
}

// Phase C: offs = local_ex + blockPrefix[bid]; seed cursor; offs[N]=E.
__global__ __launch_bounds__(256) void k_scan_c(const int* __restrict__ local_ex,
                                                const int* __restrict__ blockPrefix,
                                                int E, int* __restrict__ offs,
                                                int* __restrict__ cursor) {
    int t = threadIdx.x;
    int i = blockIdx.x * 256 + t;
    if (i < N_NODES) {
        int o = local_ex[i] + blockPrefix[blockIdx.x];
        offs[i] = o;
        cursor[i] = o;
    }
    if (i == 0) offs[N_NODES] = E;  // total degree == E (all dst in range)
}

__global__ __launch_bounds__(256) void k_scatter(const int* __restrict__ src,
                                                 const int* __restrict__ dst,
                                                 const float* __restrict__ w, int E,
                                                 int* __restrict__ cursor,
                                                 int2* __restrict__ pairs) {
    int e = blockIdx.x * 256 + threadIdx.x;
    if (e < E) {
        int d = dst[e];
        int pos = atomicAdd(&cursor[d], 1);
        pairs[pos] = make_int2(src[e], __float_as_int(w[e]));
    }
}

// ---------------- SpMM: one wave per dst node, lane = feature ----------------

__global__ __launch_bounds__(256) void k_spmm(const int* __restrict__ offs,
                                              const int2* __restrict__ pairs,
                                              const float* __restrict__ Hin,
                                              float* __restrict__ Hout) {
    int wid = (blockIdx.x * 256 + threadIdx.x) >> 6;  // node id
    int lane = threadIdx.x & 63;                      // feature id
    if (wid >= N_NODES) return;
    int beg = offs[wid], end = offs[wid + 1];
    float acc0 = 0.f, acc1 = 0.f, acc2 = 0.f, acc3 = 0.f;
    int e = beg;
    for (; e + 4 <= end; e += 4) {  // 4 gathers in flight
        int2 p0 = pairs[e];
        int2 p1 = pairs[e + 1];
        int2 p2 = pairs[e + 2];
        int2 p3 = pairs[e + 3];
        acc0 = fmaf(__int_as_float(p0.y), Hin[(size_t)p0.x * NFEAT + lane], acc0);
        acc1 = fmaf(__int_as_float(p1.y), Hin[(size_t)p1.x * NFEAT + lane], acc1);
        acc2 = fmaf(__int_as_float(p2.y), Hin[(size_t)p2.x * NFEAT + lane], acc2);
        acc3 = fmaf(__int_as_float(p3.y), Hin[(size_t)p3.x * NFEAT + lane], acc3);
    }
    for (; e < end; ++e) {
        int2 p = pairs[e];
        acc0 = fmaf(__int_as_float(p.y), Hin[(size_t)p.x * NFEAT + lane], acc0);
    }
    Hout[(size_t)wid * NFEAT + lane] = (acc0 + acc1) + (acc2 + acc3);
}

// ---------------- Dense epilogue: out = H @ W + b (fp32, vector ALU) ----------------

#define FMA4(A, S, V)                                                          \
    do {                                                                       \
        A.x = fmaf(S, V.x, A.x);                                               \
        A.y = fmaf(S, V.y, A.y);                                               \
        A.z = fmaf(S, V.z, A.z);                                               \
        A.w = fmaf(S, V.w, A.w);                                               \
    } while (0)

__global__ __launch_bounds__(256) void k_gemm(const float* __restrict__ Hin,
                                              const float* __restrict__ W,
                                              const float* __restrict__ b,
                                              float* __restrict__ out) {
    __shared__ float4 WL[64 * 16];  // W[i][j4], 16 KiB
    __shared__ float4 BL[16];
    int t = threadIdx.x;
    const float4* W4 = (const float4*)W;
    for (int k = t; k < 1024; k += 256) WL[k] = W4[k];
    if (t < 16) BL[t] = ((const float4*)b)[t];
    __syncthreads();
    int n = blockIdx.x * 256 + t;  // one node per thread
    if (n >= N_NODES) return;
    const float4* Hrow = (const float4*)(Hin + (size_t)n * NFEAT);
    float4 acc[16];
#pragma unroll
    for (int j = 0; j < 16; ++j) acc[j] = BL[j];
    for (int i4 = 0; i4 < 16; ++i4) {  // dynamic outer loop, static acc indexing inside
        float4 h = Hrow[i4];
        const float4* w0 = &WL[(i4 * 4 + 0) * 16];
        const float4* w1 = &WL[(i4 * 4 + 1) * 16];
        const float4* w2 = &WL[(i4 * 4 + 2) * 16];
        const float4* w3 = &WL[(i4 * 4 + 3) * 16];
#pragma unroll
        for (int j = 0; j < 16; ++j) {
            FMA4(acc[j], h.x, w0[j]);
            FMA4(acc[j], h.y, w1[j]);
            FMA4(acc[j], h.z, w2[j]);
            FMA4(acc[j], h.w, w3[j]);
        }
    }
    float4* o = (float4*)(out + (size_t)n * NFEAT);
#pragma unroll
    for (int j = 0; j < 16; ++j) o[j] = acc[j];
}

// ---------------- launch ----------------

extern "C" void kernel_launch(void* const* d_in, const int* in_sizes, int n_in,
                              void* d_out, int out_size, void* d_ws, size_t ws_size,
                              hipStream_t stream) {
    const int* edge_index = (const int*)d_in[0];
    const float* ew = (const float*)d_in[1];
    const float* H = (const float*)d_in[2];
    const float* W = (const float*)d_in[3];
    const float* b = (const float*)d_in[4];
    float* out = (float*)d_out;

    int E = in_sizes[1];              // 800000
    const int* src = edge_index;      // [2,E] row-major: row 0 = src
    const int* dst = edge_index + E;  // row 1 = dst

    // workspace carve-out
    char* ws = (char*)d_ws;
    size_t off = 0;
    auto alloc = [&](size_t bytes) -> void* {
        void* p = ws + off;
        off += (bytes + 255) & ~(size_t)255;
        return p;
    };
    int* counts = (int*)alloc((size_t)N_NODES * 4);
    int* offs = (int*)alloc(((size_t)N_NODES + 1) * 4);
    int* cursor = (int*)alloc((size_t)N_NODES * 4);
    int* local_ex = (int*)alloc((size_t)N_NODES * 4);
    int* blockSums = (int*)alloc((size_t)SCAN_NB * 4);
    int* blockPrefix = (int*)alloc((size_t)SCAN_NB * 4);
    int2* pairs = (int2*)alloc((size_t)E * 8);
    float* bufA = (float*)alloc((size_t)N_NODES * NFEAT * 4);
    float* bufB = (float*)alloc((size_t)N_NODES * NFEAT * 4);

    hipMemsetAsync(counts, 0, (size_t)N_NODES * 4, stream);

    int eb = (E + 255) / 256;
    k_hist<<<eb, 256, 0, stream>>>(dst, E, counts);
    k_scan_a<<<SCAN_NB, 256, 0, stream>>>(counts, local_ex, blockSums);
    k_scan_b<<<1, 256, 0, stream>>>(blockSums, blockPrefix);
    k_scan_c<<<SCAN_NB, 256, 0, stream>>>(local_ex, blockPrefix, E, offs, cursor);
    k_scatter<<<eb, 256, 0, stream>>>(src, dst, ew, E, cursor, pairs);

    int nb = (N_NODES * 64 + 255) / 256;  // 4 nodes (waves) per block
    k_spmm<<<nb, 256, 0, stream>>>(offs, pairs, H, bufA);
    k_spmm<<<nb, 256, 0, stream>>>(offs, pairs, bufA, bufB);
    k_spmm<<<nb, 256, 0, stream>>>(offs, pairs, bufB, bufA);

    k_gemm<<<(N_NODES + 255) / 256, 256, 0, stream>>>(bufA, W, b, out);
}

// Round 7
// 258.598 us; speedup vs baseline: 1.6394x; 1.2002x over previous
//
#include <hip/hip_runtime.h>

#define N_NODES 50000
#define NFEAT 64
#define NB_BUCKETS ((N_NODES + 255) / 256)  // 196 coarse buckets (dst >> 8)
#define CHUNK 4096                          // edges per block in build passes

// ---------------- CSR build: 2-pass counting sort, coalesced writes ----------------

__global__ __launch_bounds__(256) void k_bhist(const int* __restrict__ dst, int E,
                                               int* __restrict__ bucketCount) {
    __shared__ int cnt[NB_BUCKETS];
    for (int i = threadIdx.x; i < NB_BUCKETS; i += 256) cnt[i] = 0;
    __syncthreads();
    int cbeg = blockIdx.x * CHUNK;
    int cend = min(cbeg + CHUNK, E);
    for (int e = cbeg + threadIdx.x; e < cend; e += 256)
        atomicAdd(&cnt[dst[e] >> 8], 1);
    __syncthreads();
    for (int i = threadIdx.x; i < NB_BUCKETS; i += 256)
        if (cnt[i]) atomicAdd(&bucketCount[i], cnt[i]);
}

// One tiny block: exclusive scan of 196 bucket counts.
__global__ __launch_bounds__(256) void k_bscan(const int* __restrict__ bucketCount,
                                               int E, int* __restrict__ bucketBase,
                                               int* __restrict__ bucketCursor,
                                               int* __restrict__ offs) {
    __shared__ int s[256];
    int t = threadIdx.x;
    int v = (t < NB_BUCKETS) ? bucketCount[t] : 0;
    s[t] = v;
    __syncthreads();
    for (int off = 1; off < 256; off <<= 1) {
        int u = (t >= off) ? s[t - off] : 0;
        __syncthreads();
        if (t >= off) s[t] += u;
        __syncthreads();
    }
    if (t < NB_BUCKETS) {
        int b = s[t] - v;
        bucketBase[t] = b;
        bucketCursor[t] = b;
    }
    if (t == 0) {
        bucketBase[NB_BUCKETS] = E;
        offs[N_NODES] = E;
    }
}

// Place edges into bucket-major tmp. Each block reserves a contiguous range per
// bucket (one atomic per bucket), so every written range belongs to ONE block
// (= one XCD) -> no cross-XCD dirty-line duplication (was 8x write amp).
__global__ __launch_bounds__(256) void k_bplace(const int* __restrict__ src,
                                                const int* __restrict__ dst,
                                                const float* __restrict__ w, int E,
                                                int* __restrict__ bucketCursor,
                                                int2* __restrict__ tmp) {
    __shared__ int cnt[NB_BUCKETS];
    __shared__ int base[NB_BUCKETS];
    for (int i = threadIdx.x; i < NB_BUCKETS; i += 256) cnt[i] = 0;
    __syncthreads();
    int cbeg = blockIdx.x * CHUNK;
    int cend = min(cbeg + CHUNK, E);
    for (int e = cbeg + threadIdx.x; e < cend; e += 256)
        atomicAdd(&cnt[dst[e] >> 8], 1);
    __syncthreads();
    for (int i = threadIdx.x; i < NB_BUCKETS; i += 256) {
        int c = cnt[i];
        base[i] = c ? atomicAdd(&bucketCursor[i], c) : 0;
        cnt[i] = 0;  // reuse as intra-block cursor
    }
    __syncthreads();
    for (int e = cbeg + threadIdx.x; e < cend; e += 256) {
        int d = dst[e];
        int b = d >> 8;
        int r = atomicAdd(&cnt[b], 1);
        // pack: bits 16..23 = dst&255 (for pass 2), bits 0..15 = src (<65536)
        tmp[base[b] + r] = make_int2(((d & 255) << 16) | src[e], __float_as_int(w[e]));
    }
}

// One block per bucket: 256-way counting sort by dst&255 fully in LDS.
// Sequential reads, coalesced-region writes, and emits final CSR offs.
__global__ __launch_bounds__(256) void k_bsort(const int* __restrict__ bucketBase,
                                               const int2* __restrict__ tmp,
                                               int2* __restrict__ pairs,
                                               int* __restrict__ offs) {
    __shared__ int cnt[256];
    __shared__ int ex[256];
    int b = blockIdx.x;
    int t = threadIdx.x;
    int beg = bucketBase[b], end = bucketBase[b + 1];
    cnt[t] = 0;
    __syncthreads();
    for (int e = beg + t; e < end; e += 256)
        atomicAdd(&cnt[(tmp[e].x >> 16) & 255], 1);
    __syncthreads();
    int v = cnt[t];
    ex[t] = v;
    __syncthreads();
    for (int off = 1; off < 256; off <<= 1) {
        int u = (t >= off) ? ex[t - off] : 0;
        __syncthreads();
        if (t >= off) ex[t] += u;
        __syncthreads();
    }
    int myex = ex[t] - v;  // exclusive within-bucket prefix for dstLow == t
    int d = (b << 8) + t;
    if (d < N_NODES) offs[d] = beg + myex;
    cnt[t] = myex;  // reuse as within-bucket cursor
    __syncthreads();
    for (int e = beg + t; e < end; e += 256) {
        int2 kv = tmp[e];
        int c = (kv.x >> 16) & 255;
        int r = atomicAdd(&cnt[c], 1);
        pairs[beg + r] = make_int2(kv.x & 0xFFFF, kv.y);
    }
}

// ---------------- SpMM: one wave per dst node, lane = feature ----------------

__global__ __launch_bounds__(256) void k_spmm(const int* __restrict__ offs,
                                              const int2* __restrict__ pairs,
                                              const float* __restrict__ Hin,
                                              float* __restrict__ Hout) {
    int wid = (blockIdx.x * 256 + threadIdx.x) >> 6;  // node id
    int lane = threadIdx.x & 63;                      // feature id
    if (wid >= N_NODES) return;
    int beg = offs[wid], end = offs[wid + 1];
    float acc0 = 0.f, acc1 = 0.f, acc2 = 0.f, acc3 = 0.f;
    int e = beg;
    for (; e + 4 <= end; e += 4) {  // 4 gathers in flight
        int2 p0 = pairs[e];
        int2 p1 = pairs[e + 1];
        int2 p2 = pairs[e + 2];
        int2 p3 = pairs[e + 3];
        acc0 = fmaf(__int_as_float(p0.y), Hin[(size_t)p0.x * NFEAT + lane], acc0);
        acc1 = fmaf(__int_as_float(p1.y), Hin[(size_t)p1.x * NFEAT + lane], acc1);
        acc2 = fmaf(__int_as_float(p2.y), Hin[(size_t)p2.x * NFEAT + lane], acc2);
        acc3 = fmaf(__int_as_float(p3.y), Hin[(size_t)p3.x * NFEAT + lane], acc3);
    }
    for (; e < end; ++e) {
        int2 p = pairs[e];
        acc0 = fmaf(__int_as_float(p.y), Hin[(size_t)p.x * NFEAT + lane], acc0);
    }
    Hout[(size_t)wid * NFEAT + lane] = (acc0 + acc1) + (acc2 + acc3);
}

// ---------------- Dense epilogue: out = H @ W + b (fp32, vector ALU) ----------------

#define FMA4(A, S, V)                                                          \
    do {                                                                       \
        A.x = fmaf(S, V.x, A.x);                                               \
        A.y = fmaf(S, V.y, A.y);                                               \
        A.z = fmaf(S, V.z, A.z);                                               \
        A.w = fmaf(S, V.w, A.w);                                               \
    } while (0)

__global__ __launch_bounds__(256) void k_gemm(const float* __restrict__ Hin,
                                              const float* __restrict__ W,
                                              const float* __restrict__ b,
                                              float* __restrict__ out) {
    __shared__ float4 WL[64 * 16];  // 16 KiB
    __shared__ float4 BL[16];
    int t = threadIdx.x;
    const float4* W4 = (const float4*)W;
    for (int k = t; k < 1024; k += 256) WL[k] = W4[k];
    if (t < 16) BL[t] = ((const float4*)b)[t];
    __syncthreads();
    int n = blockIdx.x * 256 + t;  // one node per thread
    if (n >= N_NODES) return;
    const float4* Hrow = (const float4*)(Hin + (size_t)n * NFEAT);
    float4 acc[16];
#pragma unroll
    for (int j = 0; j < 16; ++j) acc[j] = BL[j];
    for (int i4 = 0; i4 < 16; ++i4) {
        float4 h = Hrow[i4];
        const float4* w0 = &WL[(i4 * 4 + 0) * 16];
        const float4* w1 = &WL[(i4 * 4 + 1) * 16];
        const float4* w2 = &WL[(i4 * 4 + 2) * 16];
        const float4* w3 = &WL[(i4 * 4 + 3) * 16];
#pragma unroll
        for (int j = 0; j < 16; ++j) {
            FMA4(acc[j], h.x, w0[j]);
            FMA4(acc[j], h.y, w1[j]);
            FMA4(acc[j], h.z, w2[j]);
            FMA4(acc[j], h.w, w3[j]);
        }
    }
    float4* o = (float4*)(out + (size_t)n * NFEAT);
#pragma unroll
    for (int j = 0; j < 16; ++j) o[j] = acc[j];
}

// ---------------- launch ----------------

extern "C" void kernel_launch(void* const* d_in, const int* in_sizes, int n_in,
                              void* d_out, int out_size, void* d_ws, size_t ws_size,
                              hipStream_t stream) {
    const int* edge_index = (const int*)d_in[0];
    const float* ew = (const float*)d_in[1];
    const float* H = (const float*)d_in[2];
    const float* W = (const float*)d_in[3];
    const float* b = (const float*)d_in[4];
    float* out = (float*)d_out;

    int E = in_sizes[1];              // 800000
    const int* src = edge_index;      // [2,E] row-major: row 0 = src
    const int* dst = edge_index + E;  // row 1 = dst

    // workspace carve-out
    char* ws = (char*)d_ws;
    size_t off = 0;
    auto alloc = [&](size_t bytes) -> void* {
        void* p = ws + off;
        off += (bytes + 255) & ~(size_t)255;
        return p;
    };
    int* bucketCount = (int*)alloc((size_t)NB_BUCKETS * 4);
    int* bucketBase = (int*)alloc(((size_t)NB_BUCKETS + 1) * 4);
    int* bucketCursor = (int*)alloc((size_t)NB_BUCKETS * 4);
    int* offs = (int*)alloc(((size_t)N_NODES + 1) * 4);
    int2* tmp = (int2*)alloc((size_t)E * 8);
    int2* pairs = (int2*)alloc((size_t)E * 8);
    float* bufA = (float*)alloc((size_t)N_NODES * NFEAT * 4);
    float* bufB = (float*)alloc((size_t)N_NODES * NFEAT * 4);

    hipMemsetAsync(bucketCount, 0, (size_t)NB_BUCKETS * 4, stream);

    int nch = (E + CHUNK - 1) / CHUNK;  // 196
    k_bhist<<<nch, 256, 0, stream>>>(dst, E, bucketCount);
    k_bscan<<<1, 256, 0, stream>>>(bucketCount, E, bucketBase, bucketCursor, offs);
    k_bplace<<<nch, 256, 0, stream>>>(src, dst, ew, E, bucketCursor, tmp);
    k_bsort<<<NB_BUCKETS, 256, 0, stream>>>(bucketBase, tmp, pairs, offs);

    int nb = (N_NODES * 64 + 255) / 256;  // 4 nodes (waves) per block
    k_spmm<<<nb, 256, 0, stream>>>(offs, pairs, H, bufA);
    k_spmm<<<nb, 256, 0, stream>>>(offs, pairs, bufA, bufB);
    k_spmm<<<nb, 256, 0, stream>>>(offs, pairs, bufB, bufA);

    k_gemm<<<(N_NODES + 255) / 256, 256, 0, stream>>>(bufA, W, b, out);
}

// Round 9
// 243.111 us; speedup vs baseline: 1.7438x; 1.0637x over previous
//
#include <hip/hip_runtime.h>

#define N_NODES 50000
#define NFEAT 64
#define NB_BUCKETS ((N_NODES + 255) / 256)  // 196 coarse buckets (dst >> 8)
#define CHUNK 4096                          // edges per block in build passes

#define FMA4(A, S, V)                                                          \
    do {                                                                       \
        A.x = fmaf(S, V.x, A.x);                                               \
        A.y = fmaf(S, V.y, A.y);                                               \
        A.z = fmaf(S, V.z, A.z);                                               \
        A.w = fmaf(S, V.w, A.w);                                               \
    } while (0)

// ---------------- CSR build: 2-pass counting sort, coalesced writes ----------------

__global__ __launch_bounds__(256) void k_bhist(const int* __restrict__ dst, int E,
                                               int* __restrict__ bucketCount) {
    __shared__ int cnt[NB_BUCKETS];
    for (int i = threadIdx.x; i < NB_BUCKETS; i += 256) cnt[i] = 0;
    __syncthreads();
    int cbeg = blockIdx.x * CHUNK;
    int cend = min(cbeg + CHUNK, E);
    for (int e = cbeg + threadIdx.x; e < cend; e += 256)
        atomicAdd(&cnt[dst[e] >> 8], 1);
    __syncthreads();
    for (int i = threadIdx.x; i < NB_BUCKETS; i += 256)
        if (cnt[i]) atomicAdd(&bucketCount[i], cnt[i]);
}

// One tiny block: exclusive scan of 196 bucket counts.
__global__ __launch_bounds__(256) void k_bscan(const int* __restrict__ bucketCount,
                                               int E, int* __restrict__ bucketBase,
                                               int* __restrict__ bucketCursor,
                                               int* __restrict__ offs) {
    __shared__ int s[256];
    int t = threadIdx.x;
    int v = (t < NB_BUCKETS) ? bucketCount[t] : 0;
    s[t] = v;
    __syncthreads();
    for (int off = 1; off < 256; off <<= 1) {
        int u = (t >= off) ? s[t - off] : 0;
        __syncthreads();
        if (t >= off) s[t] += u;
        __syncthreads();
    }
    if (t < NB_BUCKETS) {
        int b = s[t] - v;
        bucketBase[t] = b;
        bucketCursor[t] = b;
    }
    if (t == 0) {
        bucketBase[NB_BUCKETS] = E;
        offs[N_NODES] = E;
    }
}

// Place edges into bucket-major tmp. Each block reserves a contiguous range per
// bucket (one atomic per bucket), so every written range belongs to ONE block
// (= one XCD) -> no cross-XCD dirty-line duplication (was 8x write amp).
__global__ __launch_bounds__(256) void k_bplace(const int* __restrict__ src,
                                                const int* __restrict__ dst,
                                                const float* __restrict__ w, int E,
                                                int* __restrict__ bucketCursor,
                                                int2* __restrict__ tmp) {
    __shared__ int cnt[NB_BUCKETS];
    __shared__ int base[NB_BUCKETS];
    for (int i = threadIdx.x; i < NB_BUCKETS; i += 256) cnt[i] = 0;
    __syncthreads();
    int cbeg = blockIdx.x * CHUNK;
    int cend = min(cbeg + CHUNK, E);
    for (int e = cbeg + threadIdx.x; e < cend; e += 256)
        atomicAdd(&cnt[dst[e] >> 8], 1);
    __syncthreads();
    for (int i = threadIdx.x; i < NB_BUCKETS; i += 256) {
        int c = cnt[i];
        base[i] = c ? atomicAdd(&bucketCursor[i], c) : 0;
        cnt[i] = 0;  // reuse as intra-block cursor
    }
    __syncthreads();
    for (int e = cbeg + threadIdx.x; e < cend; e += 256) {
        int d = dst[e];
        int b = d >> 8;
        int r = atomicAdd(&cnt[b], 1);
        // pack: bits 16..23 = dst&255 (for pass 2), bits 0..15 = src (<65536)
        tmp[base[b] + r] = make_int2(((d & 255) << 16) | src[e], __float_as_int(w[e]));
    }
}

// One block per bucket: 256-way counting sort by dst&255 fully in LDS.
// Sequential reads, coalesced-region writes, and emits final CSR offs.
__global__ __launch_bounds__(256) void k_bsort(const int* __restrict__ bucketBase,
                                               const int2* __restrict__ tmp,
                                               int2* __restrict__ pairs,
                                               int* __restrict__ offs) {
    __shared__ int cnt[256];
    __shared__ int ex[256];
    int b = blockIdx.x;
    int t = threadIdx.x;
    int beg = bucketBase[b], end = bucketBase[b + 1];
    cnt[t] = 0;
    __syncthreads();
    for (int e = beg + t; e < end; e += 256)
        atomicAdd(&cnt[(tmp[e].x >> 16) & 255], 1);
    __syncthreads();
    int v = cnt[t];
    ex[t] = v;
    __syncthreads();
    for (int off = 1; off < 256; off <<= 1) {
        int u = (t >= off) ? ex[t - off] : 0;
        __syncthreads();
        if (t >= off) ex[t] += u;
        __syncthreads();
    }
    int myex = ex[t] - v;  // exclusive within-bucket prefix for dstLow == t
    int d = (b << 8) + t;
    if (d < N_NODES) offs[d] = beg + myex;
    cnt[t] = myex;  // reuse as within-bucket cursor
    __syncthreads();
    for (int e = beg + t; e < end; e += 256) {
        int2 kv = tmp[e];
        int c = (kv.x >> 16) & 255;
        int r = atomicAdd(&cnt[c], 1);
        pairs[beg + r] = make_int2(kv.x & 0xFFFF, kv.y);
    }
}

// ---------------- SpMM: 4 nodes per wave, 16 lanes x float4 per node ----------------
// Per loop slot the wave processes 4 edges (one per 16-lane group) -> ~3x fewer
// dynamic instructions than 1-node/wave, and unroll-2 gives 8 gathers in flight.

__global__ __launch_bounds__(256) void k_spmm4(const int* __restrict__ offs,
                                               const int2* __restrict__ pairs,
                                               const float* __restrict__ Hin,
                                               float* __restrict__ Hout) {
    int tid = blockIdx.x * 256 + threadIdx.x;
    int wave = tid >> 6;
    int lane = threadIdx.x & 63;
    int node = wave * 4 + (lane >> 4);  // 4 nodes per wave
    int q = lane & 15;                  // features [4q..4q+3]
    if (node >= N_NODES) return;
    int beg = offs[node], end = offs[node + 1];
    float4 acc0 = {0.f, 0.f, 0.f, 0.f}, acc1 = {0.f, 0.f, 0.f, 0.f};
    int e = beg;
    for (; e + 2 <= end; e += 2) {
        int2 p0 = pairs[e];
        int2 p1 = pairs[e + 1];
        float4 h0 = *((const float4*)(Hin + (size_t)p0.x * NFEAT) + q);
        float4 h1 = *((const float4*)(Hin + (size_t)p1.x * NFEAT) + q);
        FMA4(acc0, __int_as_float(p0.y), h0);
        FMA4(acc1, __int_as_float(p1.y), h1);
    }
    if (e < end) {
        int2 p = pairs[e];
        float4 h = *((const float4*)(Hin + (size_t)p.x * NFEAT) + q);
        FMA4(acc0, __int_as_float(p.y), h);
    }
    acc0.x += acc1.x;
    acc0.y += acc1.y;
    acc0.z += acc1.z;
    acc0.w += acc1.w;
    *((float4*)(Hout + (size_t)node * NFEAT) + q) = acc0;
}

// ---------------- Dense epilogue: out = H @ W + b (fp32, vector ALU) ----------------

__global__ __launch_bounds__(256) void k_gemm(const float* __restrict__ Hin,
                                              const float* __restrict__ W,
                                              const float* __restrict__ b,
                                              float* __restrict__ out) {
    __shared__ float4 WL[64 * 16];  // 16 KiB
    __shared__ float4 BL[16];
    int t = threadIdx.x;
    const float4* W4 = (const float4*)W;
    for (int k = t; k < 1024; k += 256) WL[k] = W4[k];
    if (t < 16) BL[t] = ((const float4*)b)[t];
    __syncthreads();
    int n = blockIdx.x * 256 + t;  // one node per thread
    if (n >= N_NODES) return;
    const float4* Hrow = (const float4*)(Hin + (size_t)n * NFEAT);
    float4 acc[16];
#pragma unroll
    for (int j = 0; j < 16; ++j) acc[j] = BL[j];
    for (int i4 = 0; i4 < 16; ++i4) {
        float4 h = Hrow[i4];
        const float4* w0 = &WL[(i4 * 4 + 0) * 16];
        const float4* w1 = &WL[(i4 * 4 + 1) * 16];
        const float4* w2 = &WL[(i4 * 4 + 2) * 16];
        const float4* w3 = &WL[(i4 * 4 + 3) * 16];
#pragma unroll
        for (int j = 0; j < 16; ++j) {
            FMA4(acc[j], h.x, w0[j]);
            FMA4(acc[j], h.y, w1[j]);
            FMA4(acc[j], h.z, w2[j]);
            FMA4(acc[j], h.w, w3[j]);
        }
    }
    float4* o = (float4*)(out + (size_t)n * NFEAT);
#pragma unroll
    for (int j = 0; j < 16; ++j) o[j] = acc[j];
}

// ---------------- launch ----------------

extern "C" void kernel_launch(void* const* d_in, const int* in_sizes, int n_in,
                              void* d_out, int out_size, void* d_ws, size_t ws_size,
                              hipStream_t stream) {
    const int* edge_index = (const int*)d_in[0];
    const float* ew = (const float*)d_in[1];
    const float* H = (const float*)d_in[2];
    const float* W = (const float*)d_in[3];
    const float* b = (const float*)d_in[4];
    float* out = (float*)d_out;

    int E = in_sizes[1];              // 800000
    const int* src = edge_index;      // [2,E] row-major: row 0 = src
    const int* dst = edge_index + E;  // row 1 = dst

    // workspace carve-out
    char* ws = (char*)d_ws;
    size_t off = 0;
    auto alloc = [&](size_t bytes) -> void* {
        void* p = ws + off;
        off += (bytes + 255) & ~(size_t)255;
        return p;
    };
    int* bucketCount = (int*)alloc((size_t)NB_BUCKETS * 4);
    int* bucketBase = (int*)alloc(((size_t)NB_BUCKETS + 1) * 4);
    int* bucketCursor = (int*)alloc((size_t)NB_BUCKETS * 4);
    int* offs = (int*)alloc(((size_t)N_NODES + 1) * 4);
    int2* tmp = (int2*)alloc((size_t)E * 8);
    int2* pairs = (int2*)alloc((size_t)E * 8);
    float* bufA = (float*)alloc((size_t)N_NODES * NFEAT * 4);
    float* bufB = (float*)alloc((size_t)N_NODES * NFEAT * 4);

    hipMemsetAsync(bucketCount, 0, (size_t)NB_BUCKETS * 4, stream);

    int nch = (E + CHUNK - 1) / CHUNK;  // 196
    k_bhist<<<nch, 256, 0, stream>>>(dst, E, bucketCount);
    k_bscan<<<1, 256, 0, stream>>>(bucketCount, E, bucketBase, bucketCursor, offs);
    k_bplace<<<nch, 256, 0, stream>>>(src, dst, ew, E, bucketCursor, tmp);
    k_bsort<<<NB_BUCKETS, 256, 0, stream>>>(bucketBase, tmp, pairs, offs);

    // 4 waves/block, 4 nodes/wave -> 16 nodes per block
    int nb = (N_NODES + 15) / 16;  // 3125 blocks
    k_spmm4<<<nb, 256, 0, stream>>>(offs, pairs, H, bufA);
    k_spmm4<<<nb, 256, 0, stream>>>(offs, pairs, bufA, bufB);
    k_spmm4<<<nb, 256, 0, stream>>>(offs, pairs, bufB, bufA);

    k_gemm<<<(N_NODES + 255) / 256, 256, 0, stream>>>(bufA, W, b, out);
}

// Round 14
// 220.561 us; speedup vs baseline: 1.9221x; 1.1022x over previous
//
#include <hip/hip_runtime.h>
#include <hip/hip_fp16.h>

#define N_NODES 50000
#define NFEAT 64
#define NB_BUCKETS ((N_NODES + 255) / 256)  // 196 coarse buckets (dst >> 8)
#define CHUNK 4096                          // edges per block in build passes

#define FMA4(A, S, V)                                                          \
    do {                                                                       \
        A.x = fmaf(S, V.x, A.x);                                               \
        A.y = fmaf(S, V.y, A.y);                                               \
        A.z = fmaf(S, V.z, A.z);                                               \
        A.w = fmaf(S, V.w, A.w);                                               \
    } while (0)

// ---------------- CSR build: 2-pass counting sort, coalesced writes ----------------

__global__ __launch_bounds__(256) void k_bhist(const int* __restrict__ dst, int E,
                                               int* __restrict__ bucketCount) {
    __shared__ int cnt[NB_BUCKETS];
    for (int i = threadIdx.x; i < NB_BUCKETS; i += 256) cnt[i] = 0;
    __syncthreads();
    int cbeg = blockIdx.x * CHUNK;
    int cend = min(cbeg + CHUNK, E);
    for (int e = cbeg + threadIdx.x; e < cend; e += 256)
        atomicAdd(&cnt[dst[e] >> 8], 1);
    __syncthreads();
    for (int i = threadIdx.x; i < NB_BUCKETS; i += 256)
        if (cnt[i]) atomicAdd(&bucketCount[i], cnt[i]);
}

// One tiny block: exclusive scan of 196 bucket counts.
__global__ __launch_bounds__(256) void k_bscan(const int* __restrict__ bucketCount,
                                               int E, int* __restrict__ bucketBase,
                                               int* __restrict__ bucketCursor,
                                               int* __restrict__ offs) {
    __shared__ int s[256];
    int t = threadIdx.x;
    int v = (t < NB_BUCKETS) ? bucketCount[t] : 0;
    s[t] = v;
    __syncthreads();
    for (int off = 1; off < 256; off <<= 1) {
        int u = (t >= off) ? s[t - off] : 0;
        __syncthreads();
        if (t >= off) s[t] += u;
        __syncthreads();
    }
    if (t < NB_BUCKETS) {
        int b = s[t] - v;
        bucketBase[t] = b;
        bucketCursor[t] = b;
    }
    if (t == 0) {
        bucketBase[NB_BUCKETS] = E;
        offs[N_NODES] = E;
    }
}

// Place edges into bucket-major tmp; block-private contiguous ranges avoid
// cross-XCD dirty-line duplication (measured 8x write amp with naive scatter).
__global__ __launch_bounds__(256) void k_bplace(const int* __restrict__ src,
                                                const int* __restrict__ dst,
                                                const float* __restrict__ w, int E,
                                                int* __restrict__ bucketCursor,
                                                int2* __restrict__ tmp) {
    __shared__ int cnt[NB_BUCKETS];
    __shared__ int base[NB_BUCKETS];
    for (int i = threadIdx.x; i < NB_BUCKETS; i += 256) cnt[i] = 0;
    __syncthreads();
    int cbeg = blockIdx.x * CHUNK;
    int cend = min(cbeg + CHUNK, E);
    for (int e = cbeg + threadIdx.x; e < cend; e += 256)
        atomicAdd(&cnt[dst[e] >> 8], 1);
    __syncthreads();
    for (int i = threadIdx.x; i < NB_BUCKETS; i += 256) {
        int c = cnt[i];
        base[i] = c ? atomicAdd(&bucketCursor[i], c) : 0;
        cnt[i] = 0;  // reuse as intra-block cursor
    }
    __syncthreads();
    for (int e = cbeg + threadIdx.x; e < cend; e += 256) {
        int d = dst[e];
        int b = d >> 8;
        int r = atomicAdd(&cnt[b], 1);
        tmp[base[b] + r] = make_int2(((d & 255) << 16) | src[e], __float_as_int(w[e]));
    }
}

// One block per bucket: 256-way counting sort by dst&255 fully in LDS.
__global__ __launch_bounds__(256) void k_bsort(const int* __restrict__ bucketBase,
                                               const int2* __restrict__ tmp,
                                               int2* __restrict__ pairs,
                                               int* __restrict__ offs) {
    __shared__ int cnt[256];
    __shared__ int ex[256];
    int b = blockIdx.x;
    int t = threadIdx.x;
    int beg = bucketBase[b], end = bucketBase[b + 1];
    cnt[t] = 0;
    __syncthreads();
    for (int e = beg + t; e < end; e += 256)
        atomicAdd(&cnt[(tmp[e].x >> 16) & 255], 1);
    __syncthreads();
    int v = cnt[t];
    ex[t] = v;
    __syncthreads();
    for (int off = 1; off < 256; off <<= 1) {
        int u = (t >= off) ? ex[t - off] : 0;
        __syncthreads();
        if (t >= off) ex[t] += u;
        __syncthreads();
    }
    int myex = ex[t] - v;
    int d = (b << 8) + t;
    if (d < N_NODES) offs[d] = beg + myex;
    cnt[t] = myex;
    __syncthreads();
    for (int e = beg + t; e < end; e += 256) {
        int2 kv = tmp[e];
        int c = (kv.x >> 16) & 255;
        int r = atomicAdd(&cnt[c], 1);
        pairs[beg + r] = make_int2(kv.x & 0xFFFF, kv.y);
    }
}

// ---------------- fp32 -> fp16 convert (for gather payload halving) ----------------

__global__ __launch_bounds__(256) void k_f2h(const float* __restrict__ in,
                                             __half* __restrict__ out, int n4) {
    int i = blockIdx.x * 256 + threadIdx.x;  // one float4 per thread
    if (i >= n4) return;
    float4 v = ((const float4*)in)[i];
    float2 packed;
    ((__half2*)&packed)[0] = __float22half2_rn(make_float2(v.x, v.y));
    ((__half2*)&packed)[1] = __float22half2_rn(make_float2(v.z, v.w));
    ((float2*)out)[i] = packed;
}

// ---------------- SpMM: 4 nodes/wave, 16 lanes x 4 feats; fp16 gathers ----------------
// Gather is 8 B/lane (128 B per row) instead of 16 B; fp32 accumulate.
// OUT_HALF=true writes fp16 (feeds next layer), false writes fp32 (feeds gemm).

template <bool OUT_HALF>
__global__ __launch_bounds__(256) void k_spmm4h(const int* __restrict__ offs,
                                                const int2* __restrict__ pairs,
                                                const __half* __restrict__ Hin,
                                                void* __restrict__ Hout_) {
    int tid = blockIdx.x * 256 + threadIdx.x;
    int wave = tid >> 6;
    int lane = threadIdx.x & 63;
    int node = wave * 4 + (lane >> 4);  // 4 nodes per wave
    int q = lane & 15;                  // features [4q..4q+3]
    if (node >= N_NODES) return;
    int beg = offs[node], end = offs[node + 1];
    float4 acc0 = {0.f, 0.f, 0.f, 0.f}, acc1 = {0.f, 0.f, 0.f, 0.f};
    int e = beg;
    for (; e + 2 <= end; e += 2) {
        int2 p0 = pairs[e];
        int2 p1 = pairs[e + 1];
        float2 r0 = *((const float2*)(Hin + (size_t)p0.x * NFEAT) + q);
        float2 r1 = *((const float2*)(Hin + (size_t)p1.x * NFEAT) + q);
        float2 a0 = __half22float2(((__half2*)&r0)[0]);
        float2 b0 = __half22float2(((__half2*)&r0)[1]);
        float2 a1 = __half22float2(((__half2*)&r1)[0]);
        float2 b1 = __half22float2(((__half2*)&r1)[1]);
        float w0 = __int_as_float(p0.y), w1 = __int_as_float(p1.y);
        acc0.x = fmaf(w0, a0.x, acc0.x);
        acc0.y = fmaf(w0, a0.y, acc0.y);
        acc0.z = fmaf(w0, b0.x, acc0.z);
        acc0.w = fmaf(w0, b0.y, acc0.w);
        acc1.x = fmaf(w1, a1.x, acc1.x);
        acc1.y = fmaf(w1, a1.y, acc1.y);
        acc1.z = fmaf(w1, b1.x, acc1.z);
        acc1.w = fmaf(w1, b1.y, acc1.w);
    }
    if (e < end) {
        int2 p = pairs[e];
        float2 r = *((const float2*)(Hin + (size_t)p.x * NFEAT) + q);
        float2 a = __half22float2(((__half2*)&r)[0]);
        float2 b = __half22float2(((__half2*)&r)[1]);
        float w = __int_as_float(p.y);
        acc0.x = fmaf(w, a.x, acc0.x);
        acc0.y = fmaf(w, a.y, acc0.y);
        acc0.z = fmaf(w, b.x, acc0.z);
        acc0.w = fmaf(w, b.y, acc0.w);
    }
    acc0.x += acc1.x;
    acc0.y += acc1.y;
    acc0.z += acc1.z;
    acc0.w += acc1.w;
    if constexpr (OUT_HALF) {
        float2 packed;
        ((__half2*)&packed)[0] = __float22half2_rn(make_float2(acc0.x, acc0.y));
        ((__half2*)&packed)[1] = __float22half2_rn(make_float2(acc0.z, acc0.w));
        *((float2*)((__half*)Hout_ + (size_t)node * NFEAT) + q) = packed;
    } else {
        *((float4*)((float*)Hout_ + (size_t)node * NFEAT) + q) = acc0;
    }
}

// ---------------- Dense epilogue: out = H @ W + b (fp32, vector ALU) ----------------

__global__ __launch_bounds__(256) void k_gemm(const float* __restrict__ Hin,
                                              const float* __restrict__ W,
                                              const float* __restrict__ b,
                                              float* __restrict__ out) {
    __shared__ float4 WL[64 * 16];  // 16 KiB
    __shared__ float4 BL[16];
    int t = threadIdx.x;
    const float4* W4 = (const float4*)W;
    for (int k = t; k < 1024; k += 256) WL[k] = W4[k];
    if (t < 16) BL[t] = ((const float4*)b)[t];
    __syncthreads();
    int n = blockIdx.x * 256 + t;  // one node per thread
    if (n >= N_NODES) return;
    const float4* Hrow = (const float4*)(Hin + (size_t)n * NFEAT);
    float4 acc[16];
#pragma unroll
    for (int j = 0; j < 16; ++j) acc[j] = BL[j];
    for (int i4 = 0; i4 < 16; ++i4) {
        float4 h = Hrow[i4];
        const float4* w0 = &WL[(i4 * 4 + 0) * 16];
        const float4* w1 = &WL[(i4 * 4 + 1) * 16];
        const float4* w2 = &WL[(i4 * 4 + 2) * 16];
        const float4* w3 = &WL[(i4 * 4 + 3) * 16];
#pragma unroll
        for (int j = 0; j < 16; ++j) {
            FMA4(acc[j], h.x, w0[j]);
            FMA4(acc[j], h.y, w1[j]);
            FMA4(acc[j], h.z, w2[j]);
            FMA4(acc[j], h.w, w3[j]);
        }
    }
    float4* o = (float4*)(out + (size_t)n * NFEAT);
#pragma unroll
    for (int j = 0; j < 16; ++j) o[j] = acc[j];
}

// ---------------- launch ----------------

extern "C" void kernel_launch(void* const* d_in, const int* in_sizes, int n_in,
                              void* d_out, int out_size, void* d_ws, size_t ws_size,
                              hipStream_t stream) {
    const int* edge_index = (const int*)d_in[0];
    const float* ew = (const float*)d_in[1];
    const float* H = (const float*)d_in[2];
    const float* W = (const float*)d_in[3];
    const float* b = (const float*)d_in[4];
    float* out = (float*)d_out;

    int E = in_sizes[1];              // 800000
    const int* src = edge_index;      // [2,E] row-major: row 0 = src
    const int* dst = edge_index + E;  // row 1 = dst

    // workspace carve-out
    char* ws = (char*)d_ws;
    size_t off = 0;
    auto alloc = [&](size_t bytes) -> void* {
        void* p = ws + off;
        off += (bytes + 255) & ~(size_t)255;
        return p;
    };
    int* bucketCount = (int*)alloc((size_t)NB_BUCKETS * 4);
    int* bucketBase = (int*)alloc(((size_t)NB_BUCKETS + 1) * 4);
    int* bucketCursor = (int*)alloc((size_t)NB_BUCKETS * 4);
    int* offs = (int*)alloc(((size_t)N_NODES + 1) * 4);
    int2* tmp = (int2*)alloc((size_t)E * 8);
    int2* pairs = (int2*)alloc((size_t)E * 8);
    __half* h0 = (__half*)alloc((size_t)N_NODES * NFEAT * 2);  // fp16 ping
    __half* h1 = (__half*)alloc((size_t)N_NODES * NFEAT * 2);  // fp16 pong
    float* bufA = (float*)alloc((size_t)N_NODES * NFEAT * 4);  // fp32 H3

    hipMemsetAsync(bucketCount, 0, (size_t)NB_BUCKETS * 4, stream);

    int nch = (E + CHUNK - 1) / CHUNK;  // 196
    k_bhist<<<nch, 256, 0, stream>>>(dst, E, bucketCount);
    k_bscan<<<1, 256, 0, stream>>>(bucketCount, E, bucketBase, bucketCursor, offs);
    k_bplace<<<nch, 256, 0, stream>>>(src, dst, ew, E, bucketCursor, tmp);
    k_bsort<<<NB_BUCKETS, 256, 0, stream>>>(bucketBase, tmp, pairs, offs);

    // H (fp32) -> h0 (fp16)
    int n4 = N_NODES * NFEAT / 4;  // 800000 float4s
    k_f2h<<<(n4 + 255) / 256, 256, 0, stream>>>(H, h0, n4);

    int nb = (N_NODES + 15) / 16;  // 3125 blocks, 16 nodes/block
    k_spmm4h<true><<<nb, 256, 0, stream>>>(offs, pairs, h0, h1);    // L1: h0->h1
    k_spmm4h<true><<<nb, 256, 0, stream>>>(offs, pairs, h1, h0);    // L2: h1->h0
    k_spmm4h<false><<<nb, 256, 0, stream>>>(offs, pairs, h0, bufA); // L3: h0->fp32

    k_gemm<<<(N_NODES + 255) / 256, 256, 0, stream>>>(bufA, W, b, out);
}